// Round 5
// baseline (794.856 us; speedup 1.0000x reference)
//
#include <hip/hip_runtime.h>
#include <stdint.h>

typedef unsigned short ushort_t;
typedef __attribute__((ext_vector_type(8))) short bf16x8;
typedef __attribute__((ext_vector_type(4))) short s16x4;
typedef __attribute__((ext_vector_type(4))) float f32x4;
typedef __attribute__((ext_vector_type(4))) unsigned short us4;

#define DEV __device__ __forceinline__

DEV ushort_t f2bf(float f) {
    unsigned int u = __float_as_uint(f);
    u += 0x7fffu + ((u >> 16) & 1u);
    return (ushort_t)(u >> 16);
}

DEV void async16(const ushort_t* g, ushort_t* l) {
    __builtin_amdgcn_global_load_lds(
        (const __attribute__((address_space(1))) void*)g,
        (__attribute__((address_space(3))) void*)l,
        16, 0, 0);
}

// Barrier that drains LDS ops only — leaves global loads in flight (the
// compiler's __syncthreads always drains vmcnt(0), killing prefetch).
DEV void barrier_lgkm() {
    __asm__ volatile("s_waitcnt lgkmcnt(0)\n\ts_barrier" ::: "memory");
}

// ---------------------------------------------------------------------------
// f32 -> bf16 conversion of x and the four weight matrices (one launch).
// ---------------------------------------------------------------------------
__global__ void convert_kernel(const float* __restrict__ x, const float* __restrict__ wq,
                               const float* __restrict__ wk, const float* __restrict__ wv,
                               const float* __restrict__ wo,
                               ushort_t* __restrict__ xb, ushort_t* __restrict__ wqb,
                               ushort_t* __restrict__ wkb, ushort_t* __restrict__ wvb,
                               ushort_t* __restrict__ wob)
{
    const int i = blockIdx.x * 256 + threadIdx.x; // float4 index, 1048576 total
    const float* src; ushort_t* dst; int off;
    if (i < 524288)      { src = x;  dst = xb;  off = i; }
    else if (i < 655360) { src = wq; dst = wqb; off = i - 524288; }
    else if (i < 786432) { src = wk; dst = wkb; off = i - 655360; }
    else if (i < 917504) { src = wv; dst = wvb; off = i - 786432; }
    else                 { src = wo; dst = wob; off = i - 917504; }
    const float4 v = ((const float4*)src)[off];
    us4 o;
    o[0] = f2bf(v.x); o[1] = f2bf(v.y); o[2] = f2bf(v.z); o[3] = f2bf(v.w);
    ((us4*)dst)[off] = o;
}

// ---------------------------------------------------------------------------
// Fused QKV projection GEMM: C = x[8192][256] * Wqkv[6144][256]^T,
// 128x128 tile, 4 waves. Column block routes to q / k (row-major) or v
// (transposed [b][h][d][l]).
// ---------------------------------------------------------------------------
__global__ __launch_bounds__(256, 2) void gemm_qkv_kernel(
    const ushort_t* __restrict__ A, const ushort_t* __restrict__ Bm,
    void* __restrict__ C0, void* __restrict__ C1, void* __restrict__ C2)
{
    __shared__ ushort_t At[128 * 64];
    __shared__ ushort_t Bt[128 * 64];

    const int tid  = threadIdx.x;
    const int wave = tid >> 6;
    const int lane = tid & 63;
    const int quad = lane >> 4;
    const int l15  = lane & 15;
    const int mhalf = wave >> 1;
    const int nhalf = wave & 1;
    const int m0 = blockIdx.x * 128;
    const int n0 = blockIdx.y * 128;
    const int K = 256;

    f32x4 acc[4][4];
#pragma unroll
    for (int mf = 0; mf < 4; ++mf)
#pragma unroll
        for (int nf = 0; nf < 4; ++nf)
#pragma unroll
            for (int r = 0; r < 4; ++r) acc[mf][nf][r] = 0.f;

    const int crow = (lane & 7) ^ (lane >> 3);

    for (int k0 = 0; k0 < K; k0 += 64) {
        __syncthreads();
#pragma unroll
        for (int t = 0; t < 4; ++t) {
            const int row = wave * 32 + t * 8 + (lane >> 3);
            async16(A + (size_t)(m0 + row) * K + k0 + crow * 8,
                    At + (wave * 32 + t * 8) * 64 + lane * 8);
            async16(Bm + (size_t)(n0 + row) * K + k0 + crow * 8,
                    Bt + (wave * 32 + t * 8) * 64 + lane * 8);
        }
        __syncthreads();
#pragma unroll
        for (int ks = 0; ks < 2; ++ks) {
            bf16x8 af[4], bf[4];
#pragma unroll
            for (int mf = 0; mf < 4; ++mf) {
                const int ml = mhalf * 64 + mf * 16 + l15;
                const int c = (ks * 4 + quad) ^ (ml & 7);
                af[mf] = *(const bf16x8*)(At + ml * 64 + c * 8);
            }
#pragma unroll
            for (int nf = 0; nf < 4; ++nf) {
                const int nl = nhalf * 64 + nf * 16 + l15;
                const int c = (ks * 4 + quad) ^ (nl & 7);
                bf[nf] = *(const bf16x8*)(Bt + nl * 64 + c * 8);
            }
#pragma unroll
            for (int mf = 0; mf < 4; ++mf)
#pragma unroll
                for (int nf = 0; nf < 4; ++nf)
                    acc[mf][nf] = __builtin_amdgcn_mfma_f32_16x16x32_bf16(
                        af[mf], bf[nf], acc[mf][nf], 0, 0, 0);
        }
    }

    const int sel = n0 >> 11;               // 0:q 1:k 2:v
    if (sel == 2) {
#pragma unroll
        for (int mf = 0; mf < 4; ++mf)
#pragma unroll
            for (int nf = 0; nf < 4; ++nf) {
                const int row = m0 + mhalf * 64 + mf * 16 + quad * 4;
                const int colv = (n0 - 4096) + nhalf * 64 + nf * 16 + l15;
                const int b_ = row >> 11, l_ = row & 2047;
                const int h_ = colv >> 8, d_ = colv & 255;
                us4 pk;
#pragma unroll
                for (int r = 0; r < 4; ++r) pk[r] = f2bf(acc[mf][nf][r]);
                *(us4*)((ushort_t*)C2 +
                        (((size_t)(b_ * 8 + h_) * 256 + d_) * 2048 + l_)) = pk;
            }
    } else {
        ushort_t* dst = sel ? (ushort_t*)C1 : (ushort_t*)C0;
#pragma unroll
        for (int mf = 0; mf < 4; ++mf)
#pragma unroll
            for (int nf = 0; nf < 4; ++nf)
#pragma unroll
                for (int r = 0; r < 4; ++r) {
                    const int row = m0 + mhalf * 64 + mf * 16 + quad * 4 + r;
                    const int col = (n0 & 2047) + nhalf * 64 + nf * 16 + l15;
                    dst[(size_t)row * 2048 + col] = f2bf(acc[mf][nf][r]);
                }
    }
}

// ---------------------------------------------------------------------------
// Output projection GEMM, 64x128 tile (grid 128x2 = 256 blocks -> all CUs).
// ---------------------------------------------------------------------------
__global__ __launch_bounds__(256, 4) void gemm_out_kernel(
    const ushort_t* __restrict__ A, const ushort_t* __restrict__ Bm,
    float* __restrict__ C)
{
    __shared__ ushort_t At[64 * 64];    // 8 KB
    __shared__ ushort_t Bt[128 * 64];   // 16 KB

    const int tid  = threadIdx.x;
    const int wave = tid >> 6;
    const int lane = tid & 63;
    const int quad = lane >> 4;
    const int l15  = lane & 15;
    const int mhalf = wave >> 1;
    const int nhalf = wave & 1;
    const int m0 = blockIdx.x * 64;
    const int n0 = blockIdx.y * 128;

    f32x4 acc[2][4];
#pragma unroll
    for (int mf = 0; mf < 2; ++mf)
#pragma unroll
        for (int nf = 0; nf < 4; ++nf)
#pragma unroll
            for (int r = 0; r < 4; ++r) acc[mf][nf][r] = 0.f;

    const int crow = (lane & 7) ^ (lane >> 3);

    for (int k0 = 0; k0 < 2048; k0 += 64) {
        __syncthreads();
#pragma unroll
        for (int t = 0; t < 2; ++t) {
            const int row = wave * 16 + t * 8 + (lane >> 3);
            async16(A + (size_t)(m0 + row) * 2048 + k0 + crow * 8,
                    At + (wave * 16 + t * 8) * 64 + lane * 8);
        }
#pragma unroll
        for (int t = 0; t < 4; ++t) {
            const int row = wave * 32 + t * 8 + (lane >> 3);
            async16(Bm + (size_t)(n0 + row) * 2048 + k0 + crow * 8,
                    Bt + (wave * 32 + t * 8) * 64 + lane * 8);
        }
        __syncthreads();
#pragma unroll
        for (int ks = 0; ks < 2; ++ks) {
            bf16x8 af[2], bf[4];
#pragma unroll
            for (int mf = 0; mf < 2; ++mf) {
                const int ml = mhalf * 32 + mf * 16 + l15;
                const int c = (ks * 4 + quad) ^ (ml & 7);
                af[mf] = *(const bf16x8*)(At + ml * 64 + c * 8);
            }
#pragma unroll
            for (int nf = 0; nf < 4; ++nf) {
                const int nl = nhalf * 64 + nf * 16 + l15;
                const int c = (ks * 4 + quad) ^ (nl & 7);
                bf[nf] = *(const bf16x8*)(Bt + nl * 64 + c * 8);
            }
#pragma unroll
            for (int mf = 0; mf < 2; ++mf)
#pragma unroll
                for (int nf = 0; nf < 4; ++nf)
                    acc[mf][nf] = __builtin_amdgcn_mfma_f32_16x16x32_bf16(
                        af[mf], bf[nf], acc[mf][nf], 0, 0, 0);
        }
    }

#pragma unroll
    for (int mf = 0; mf < 2; ++mf)
#pragma unroll
        for (int nf = 0; nf < 4; ++nf)
#pragma unroll
            for (int r = 0; r < 4; ++r) {
                const int row = m0 + mhalf * 32 + mf * 16 + quad * 4 + r;
                const int col = n0 + nhalf * 64 + nf * 16 + l15;
                C[(size_t)row * 256 + col] = acc[mf][nf][r];
            }
}

// ---------------------------------------------------------------------------
// Pass 1: Z_i = sum_j exp(s_ij/16), register-staged pipelined K tiles (32 j).
// Wave (ihalf,jhalf): quadrant 32 i x 16 j. 2 lgkm-only barriers/tile; the
// global loads for tile t+1 stay in flight across them (vm wait lands one
// compute-phase later, hidden).
// ---------------------------------------------------------------------------
__global__ __launch_bounds__(256, 3) void pass1_kernel(
    const ushort_t* __restrict__ q_ws, const ushort_t* __restrict__ k_ws,
    float* __restrict__ rz_ws)
{
    __shared__ ushort_t Kt[32 * 256];   // 16 KB, chunk-swizzled
    __shared__ float zred[2][64];

    const float SCALE = 0.0625f;        // 1/sqrt(256)
    const int tid  = threadIdx.x;
    const int wave = tid >> 6;
    const int lane = tid & 63;
    const int quad = lane >> 4;
    const int l15  = lane & 15;
    const int ihalf = wave >> 1;
    const int jhalf = wave & 1;

    const int g  = blockIdx.x;
    const int bh = ((g >> 8) << 3) | (g & 7);
    const int it = (g >> 3) & 31;
    const int b = bh >> 3, h = bh & 7;
    const int i0 = it * 64;

    const size_t qkbase = (size_t)b * 2048 * 2048 + (size_t)h * 256;

    bf16x8 qf[2][8];
#pragma unroll
    for (int ng = 0; ng < 2; ++ng) {
        const int i_l = ihalf * 32 + ng * 16 + l15;
        const ushort_t* qr = q_ws + qkbase + (size_t)(i0 + i_l) * 2048;
#pragma unroll
        for (int ks = 0; ks < 8; ++ks)
            qf[ng][ks] = *(const bf16x8*)(qr + ks * 32 + quad * 8);
    }

    // staging registers + address helpers
    const int srow = wave * 8 + (lane >> 5);          // + t*2
    const int scol = (lane & 31) ^ (srow & 7);        // 16B chunk in row
    const ushort_t* kbase = k_ws + qkbase + (size_t)srow * 2048 + scol * 8;
    uint4 kst[4];
#pragma unroll
    for (int t = 0; t < 4; ++t)
        kst[t] = *(const uint4*)(kbase + (size_t)(t * 2) * 2048);

    float z[2] = {0.f, 0.f};

    for (int jt = 0; jt < 64; ++jt) {
        barrier_lgkm();                               // readers of Kt done
#pragma unroll
        for (int t = 0; t < 4; ++t)
            *(uint4*)(Kt + (wave * 8 + t * 2) * 256 + lane * 8) = kst[t];
        if (jt < 63) {
            const ushort_t* kb = kbase + (size_t)(jt + 1) * 32 * 2048;
#pragma unroll
            for (int t = 0; t < 4; ++t)
                kst[t] = *(const uint4*)(kb + (size_t)(t * 2) * 2048);
        }
        barrier_lgkm();                               // writes visible

        f32x4 sacc[2];
#pragma unroll
        for (int ng = 0; ng < 2; ++ng)
#pragma unroll
            for (int r = 0; r < 4; ++r) sacc[ng][r] = 0.f;

#pragma unroll
        for (int ks = 0; ks < 8; ++ks) {
            const int j_l = jhalf * 16 + l15;
            const int c = (ks * 4 + quad) ^ (j_l & 7);
            const bf16x8 af = *(const bf16x8*)(Kt + j_l * 256 + c * 8);
#pragma unroll
            for (int ng = 0; ng < 2; ++ng)
                sacc[ng] = __builtin_amdgcn_mfma_f32_16x16x32_bf16(
                    af, qf[ng][ks], sacc[ng], 0, 0, 0);
        }
#pragma unroll
        for (int ng = 0; ng < 2; ++ng)
#pragma unroll
            for (int r = 0; r < 4; ++r)
                z[ng] += __expf(sacc[ng][r] * SCALE);
    }

#pragma unroll
    for (int ng = 0; ng < 2; ++ng) {
        z[ng] += __shfl_xor(z[ng], 16);
        z[ng] += __shfl_xor(z[ng], 32);
    }
    __syncthreads();
    if (quad == 0) {
#pragma unroll
        for (int ng = 0; ng < 2; ++ng)
            zred[jhalf][ihalf * 32 + ng * 16 + l15] = z[ng];
    }
    __syncthreads();
    if (tid < 64)
        rz_ws[(size_t)bh * 2048 + i0 + tid] = 1.0f / (zred[0][tid] + zred[1][tid]);
}

// ---------------------------------------------------------------------------
// Pass 2: causal w = exp(exp(s/16)/Z); PV; divide by sum(w).
// 32-j tiles, register-staged pipelined K+V, quadrant waves (ihalf,jhalf):
//   QK: 32 i x 16 j quadrant; w -> shared W[64 i][32 j] (us4 XOR swizzle);
//   PV: i-half x d-half (128 d), K=32, bv shared across mg.
// 3 lgkm-only barriers/tile; prefetch loads never drained in-loop.
// ---------------------------------------------------------------------------
__global__ __launch_bounds__(256, 2) void pass2_kernel(
    const ushort_t* __restrict__ q_ws, const ushort_t* __restrict__ k_ws,
    const ushort_t* __restrict__ vt_ws, const float* __restrict__ rz_ws,
    ushort_t* __restrict__ attn_out)
{
    __shared__ ushort_t Kt[32 * 256];   // 16 KB
    __shared__ ushort_t Vt[256 * 32];   // 16 KB
    __shared__ ushort_t Wt[64 * 32];    // 4 KB
    __shared__ float dred[128];

    const float SCALE = 0.0625f;
    const int tid  = threadIdx.x;
    const int wave = tid >> 6;
    const int lane = tid & 63;
    const int quad = lane >> 4;
    const int l15  = lane & 15;
    const int ihalf = wave >> 1;
    const int jhalf = wave & 1;

    const int g  = blockIdx.x;
    const int bh = ((g >> 8) << 3) | (g & 7);
    const int it = 31 - ((g >> 3) & 31);      // heavy blocks dispatched first
    const int b = bh >> 3, h = bh & 7;
    const int i0 = it * 64;
    const int jtmax = 2 * it + 1;

    const size_t qkbase = (size_t)b * 2048 * 2048 + (size_t)h * 256;
    const size_t vtbase = (size_t)bh * 256 * 2048;

    bf16x8 qf[2][8];
#pragma unroll
    for (int ng = 0; ng < 2; ++ng) {
        const int i_l = ihalf * 32 + ng * 16 + l15;
        const ushort_t* qr = q_ws + qkbase + (size_t)(i0 + i_l) * 2048;
#pragma unroll
        for (int ks = 0; ks < 8; ++ks)
            qf[ng][ks] = *(const bf16x8*)(qr + ks * 32 + quad * 8);
    }
    float rzrow[2];
#pragma unroll
    for (int ng = 0; ng < 2; ++ng)
        rzrow[ng] = rz_ws[(size_t)bh * 2048 + i0 + ihalf * 32 + ng * 16 + l15];

    // staging addresses (K: 32 rows x 512B; V: 256 rows x 64B)
    const int krow = wave * 8 + (lane >> 5);
    const int kcol = (lane & 31) ^ (krow & 7);
    const ushort_t* kbase = k_ws + qkbase + (size_t)krow * 2048 + kcol * 8;
    const int vrow = wave * 64 + (lane >> 2);
    const int vcol = (lane & 3) ^ (vrow & 3);
    const ushort_t* vbase = vt_ws + vtbase + (size_t)vrow * 2048 + vcol * 8;

    uint4 kst[4], vst[4];
#pragma unroll
    for (int t = 0; t < 4; ++t) {
        kst[t] = *(const uint4*)(kbase + (size_t)(t * 2) * 2048);
        vst[t] = *(const uint4*)(vbase + (size_t)(t * 16) * 2048);
    }

    f32x4 oacc[2][8];
#pragma unroll
    for (int mg = 0; mg < 2; ++mg)
#pragma unroll
        for (int nf = 0; nf < 8; ++nf)
#pragma unroll
            for (int r = 0; r < 4; ++r) oacc[mg][nf][r] = 0.f;
    float den[2] = {0.f, 0.f};

    const int iblo = it * 4 + ihalf * 2;      // wave's first 16-blk of i

    for (int jt = 0; jt <= jtmax; ++jt) {
        barrier_lgkm();                       // prev tile's LDS readers done
#pragma unroll
        for (int t = 0; t < 4; ++t) {
            *(uint4*)(Kt + (wave * 8 + t * 2) * 256 + lane * 8) = kst[t];
            *(uint4*)(Vt + (wave * 64 + t * 16) * 32 + lane * 8) = vst[t];
        }
        if (jt < jtmax) {
            const ushort_t* kb = kbase + (size_t)(jt + 1) * 32 * 2048;
            const ushort_t* vb = vbase + (size_t)(jt + 1) * 32;
#pragma unroll
            for (int t = 0; t < 4; ++t) {
                kst[t] = *(const uint4*)(kb + (size_t)(t * 2) * 2048);
                vst[t] = *(const uint4*)(vb + (size_t)(t * 16) * 2048);
            }
        }
        barrier_lgkm();                       // staged tile visible

        // ---------------- QK quadrant + w ----------------
        const int jb16 = jt * 2 + jhalf;
        if (jb16 <= iblo + 1) {               // not fully masked
            f32x4 sacc[2];
#pragma unroll
            for (int ng = 0; ng < 2; ++ng)
#pragma unroll
                for (int r = 0; r < 4; ++r) sacc[ng][r] = 0.f;
#pragma unroll
            for (int ks = 0; ks < 8; ++ks) {
                const int j_l = jhalf * 16 + l15;
                const int c = (ks * 4 + quad) ^ (j_l & 7);
                const bf16x8 af = *(const bf16x8*)(Kt + j_l * 256 + c * 8);
#pragma unroll
                for (int ng = 0; ng < 2; ++ng)
                    sacc[ng] = __builtin_amdgcn_mfma_f32_16x16x32_bf16(
                        af, qf[ng][ks], sacc[ng], 0, 0, 0);
            }
            const bool need_mask = (jb16 >= iblo);
#pragma unroll
            for (int ng = 0; ng < 2; ++ng) {
                // di = i_global - j_global(base of this lane's 4 j)
                const int di = (i0 + ihalf * 32 + ng * 16 + l15)
                             - (jt * 32 + jhalf * 16 + quad * 4);
                us4 wp;
#pragma unroll
                for (int r = 0; r < 4; ++r) {
                    const float p = __expf(sacc[ng][r] * SCALE) * rzrow[ng];
                    float w = __expf(p);
                    if (need_mask && (r > di)) w = 0.f;
                    den[ng] += w;
                    wp[r] = f2bf(w);
                }
                const int row = ihalf * 32 + ng * 16 + l15;
                const int c = (jhalf * 4 + quad) ^ (l15 & 7);
                *(us4*)(Wt + row * 32 + c * 4) = wp;
            }
        } else {                              // fully masked: zero-fill W
            const us4 zz = {0, 0, 0, 0};
#pragma unroll
            for (int ng = 0; ng < 2; ++ng) {
                const int row = ihalf * 32 + ng * 16 + l15;
                const int c = (jhalf * 4 + quad) ^ (l15 & 7);
                *(us4*)(Wt + row * 32 + c * 4) = zz;
            }
        }
        barrier_lgkm();                       // W visible (vm still in flight)

        // ---------------- PV: i-half (ihalf) x d-half (jhalf) ----------------
        if (jt <= it * 2 + ihalf) {           // any unmasked j for this i-half
            bf16x8 aw[2];
#pragma unroll
            for (int mg = 0; mg < 2; ++mg) {
                const int row = ihalf * 32 + mg * 16 + l15;
                const s16x4 lo = *(const s16x4*)(Wt + row * 32 + ((2 * quad)     ^ (l15 & 7)) * 4);
                const s16x4 hi = *(const s16x4*)(Wt + row * 32 + ((2 * quad + 1) ^ (l15 & 7)) * 4);
                union { s16x4 h[2]; bf16x8 v; } u;
                u.h[0] = lo; u.h[1] = hi;
                aw[mg] = u.v;
            }
#pragma unroll
            for (int nf = 0; nf < 8; ++nf) {
                const int d = jhalf * 128 + nf * 16 + l15;
                const int c = quad ^ (d & 3);
                const bf16x8 bv = *(const bf16x8*)(Vt + d * 32 + c * 8);
                oacc[0][nf] = __builtin_amdgcn_mfma_f32_16x16x32_bf16(aw[0], bv, oacc[0][nf], 0, 0, 0);
                oacc[1][nf] = __builtin_amdgcn_mfma_f32_16x16x32_bf16(aw[1], bv, oacc[1][nf], 0, 0, 0);
            }
        }
    }

    // ---------------- epilogue: merge den across jhalf, scale, store --------
#pragma unroll
    for (int ng = 0; ng < 2; ++ng) {
        den[ng] += __shfl_xor(den[ng], 16);
        den[ng] += __shfl_xor(den[ng], 32);
    }
    __syncthreads();
    if (quad == 0) {
#pragma unroll
        for (int ng = 0; ng < 2; ++ng)
            dred[(ihalf * 2 + jhalf) * 32 + ng * 16 + l15] = den[ng];
    }
    __syncthreads();
#pragma unroll
    for (int mg = 0; mg < 2; ++mg) {
#pragma unroll
        for (int r = 0; r < 4; ++r) {
            const int il = mg * 16 + quad * 4 + r;
            const float dt = dred[(ihalf * 2) * 32 + il] + dred[(ihalf * 2 + 1) * 32 + il];
            const float rd = 1.0f / dt;
            ushort_t* orow = attn_out + qkbase + (size_t)(i0 + ihalf * 32 + il) * 2048;
#pragma unroll
            for (int nf = 0; nf < 8; ++nf)
                orow[jhalf * 128 + nf * 16 + l15] = f2bf(oacc[mg][nf][r] * rd);
        }
    }
}

// ---------------------------------------------------------------------------
extern "C" void kernel_launch(void* const* d_in, const int* in_sizes, int n_in,
                              void* d_out, int out_size, void* d_ws, size_t ws_size,
                              hipStream_t stream) {
    const float* x  = (const float*)d_in[0];
    const float* Wq = (const float*)d_in[1];
    const float* Wk = (const float*)d_in[2];
    const float* Wv = (const float*)d_in[3];
    const float* Wo = (const float*)d_in[4];

    char* ws = (char*)d_ws;
    ushort_t* xb    = (ushort_t*)(ws);
    ushort_t* wqb   = (ushort_t*)(ws + 4194304);   // wq/wk/wv contiguous -> [6144][256]
    ushort_t* wkb   = (ushort_t*)(ws + 5242880);
    ushort_t* wvb   = (ushort_t*)(ws + 6291456);
    ushort_t* wob   = (ushort_t*)(ws + 7340032);
    ushort_t* q_ws  = (ushort_t*)(ws + 8388608);
    ushort_t* k_ws  = (ushort_t*)(ws + 41943040);
    ushort_t* vt_ws = (ushort_t*)(ws + 75497472);
    ushort_t* ao_ws = (ushort_t*)(ws + 109051904);
    float*    rz_ws = (float*)   (ws + 142606336);

    convert_kernel<<<4096, 256, 0, stream>>>(x, Wq, Wk, Wv, Wo, xb, wqb, wkb, wvb, wob);

    gemm_qkv_kernel<<<dim3(64, 48), 256, 0, stream>>>(xb, wqb, q_ws, k_ws, vt_ws);

    pass1_kernel<<<1024, 256, 0, stream>>>(q_ws, k_ws, rz_ws);
    pass2_kernel<<<1024, 256, 0, stream>>>(q_ws, k_ws, vt_ws, rz_ws, ao_ws);

    gemm_out_kernel<<<dim3(128, 2), 256, 0, stream>>>(ao_ws, wob, (float*)d_out);
}

// Round 6
// 375.486 us; speedup vs baseline: 2.1169x; 2.1169x over previous
//
#include <hip/hip_runtime.h>
#include <stdint.h>

typedef unsigned short ushort_t;
typedef __attribute__((ext_vector_type(8))) short bf16x8;
typedef __attribute__((ext_vector_type(4))) short s16x4;
typedef __attribute__((ext_vector_type(4))) float f32x4;
typedef __attribute__((ext_vector_type(4))) unsigned short us4;

#define DEV __device__ __forceinline__

DEV ushort_t f2bf(float f) {
    unsigned int u = __float_as_uint(f);
    u += 0x7fffu + ((u >> 16) & 1u);
    return (ushort_t)(u >> 16);
}

DEV void async16(const ushort_t* g, ushort_t* l) {
    __builtin_amdgcn_global_load_lds(
        (const __attribute__((address_space(1))) void*)g,
        (__attribute__((address_space(3))) void*)l,
        16, 0, 0);
}

// Barriers that do NOT drain vmcnt(0) — prefetch DMAs stay in flight.
DEV void barrier_lgkm() {
    __asm__ volatile("s_waitcnt lgkmcnt(0)\n\ts_barrier" ::: "memory");
}
DEV void barrier_vm8() {   // wait until <=8 vmem outstanding (old tile landed)
    __asm__ volatile("s_waitcnt vmcnt(8)\n\ts_barrier" ::: "memory");
}
DEV void barrier_vm0() {
    __asm__ volatile("s_waitcnt vmcnt(0)\n\ts_barrier" ::: "memory");
}

// ---------------------------------------------------------------------------
// f32 -> bf16 conversion of x and the four weight matrices (one launch).
// ---------------------------------------------------------------------------
__global__ void convert_kernel(const float* __restrict__ x, const float* __restrict__ wq,
                               const float* __restrict__ wk, const float* __restrict__ wv,
                               const float* __restrict__ wo,
                               ushort_t* __restrict__ xb, ushort_t* __restrict__ wqb,
                               ushort_t* __restrict__ wkb, ushort_t* __restrict__ wvb,
                               ushort_t* __restrict__ wob)
{
    const int i = blockIdx.x * 256 + threadIdx.x; // float4 index, 1048576 total
    const float* src; ushort_t* dst; int off;
    if (i < 524288)      { src = x;  dst = xb;  off = i; }
    else if (i < 655360) { src = wq; dst = wqb; off = i - 524288; }
    else if (i < 786432) { src = wk; dst = wkb; off = i - 655360; }
    else if (i < 917504) { src = wv; dst = wvb; off = i - 786432; }
    else                 { src = wo; dst = wob; off = i - 917504; }
    const float4 v = ((const float4*)src)[off];
    us4 o;
    o[0] = f2bf(v.x); o[1] = f2bf(v.y); o[2] = f2bf(v.z); o[3] = f2bf(v.w);
    ((us4*)dst)[off] = o;
}

// ---------------------------------------------------------------------------
// Fused QKV projection GEMM: C = x[8192][256] * Wqkv[6144][256]^T,
// 128x128 tile, 4 waves. Column block routes to q / k (row-major) or v
// (transposed [b][h][d][l]).
// ---------------------------------------------------------------------------
__global__ __launch_bounds__(256, 2) void gemm_qkv_kernel(
    const ushort_t* __restrict__ A, const ushort_t* __restrict__ Bm,
    void* __restrict__ C0, void* __restrict__ C1, void* __restrict__ C2)
{
    __shared__ ushort_t At[128 * 64];
    __shared__ ushort_t Bt[128 * 64];

    const int tid  = threadIdx.x;
    const int wave = tid >> 6;
    const int lane = tid & 63;
    const int quad = lane >> 4;
    const int l15  = lane & 15;
    const int mhalf = wave >> 1;
    const int nhalf = wave & 1;
    const int m0 = blockIdx.x * 128;
    const int n0 = blockIdx.y * 128;
    const int K = 256;

    f32x4 acc[4][4];
#pragma unroll
    for (int mf = 0; mf < 4; ++mf)
#pragma unroll
        for (int nf = 0; nf < 4; ++nf)
#pragma unroll
            for (int r = 0; r < 4; ++r) acc[mf][nf][r] = 0.f;

    const int crow = (lane & 7) ^ (lane >> 3);

    for (int k0 = 0; k0 < K; k0 += 64) {
        __syncthreads();
#pragma unroll
        for (int t = 0; t < 4; ++t) {
            const int row = wave * 32 + t * 8 + (lane >> 3);
            async16(A + (size_t)(m0 + row) * K + k0 + crow * 8,
                    At + (wave * 32 + t * 8) * 64 + lane * 8);
            async16(Bm + (size_t)(n0 + row) * K + k0 + crow * 8,
                    Bt + (wave * 32 + t * 8) * 64 + lane * 8);
        }
        __syncthreads();
#pragma unroll
        for (int ks = 0; ks < 2; ++ks) {
            bf16x8 af[4], bf[4];
#pragma unroll
            for (int mf = 0; mf < 4; ++mf) {
                const int ml = mhalf * 64 + mf * 16 + l15;
                const int c = (ks * 4 + quad) ^ (ml & 7);
                af[mf] = *(const bf16x8*)(At + ml * 64 + c * 8);
            }
#pragma unroll
            for (int nf = 0; nf < 4; ++nf) {
                const int nl = nhalf * 64 + nf * 16 + l15;
                const int c = (ks * 4 + quad) ^ (nl & 7);
                bf[nf] = *(const bf16x8*)(Bt + nl * 64 + c * 8);
            }
#pragma unroll
            for (int mf = 0; mf < 4; ++mf)
#pragma unroll
                for (int nf = 0; nf < 4; ++nf)
                    acc[mf][nf] = __builtin_amdgcn_mfma_f32_16x16x32_bf16(
                        af[mf], bf[nf], acc[mf][nf], 0, 0, 0);
        }
    }

    const int sel = n0 >> 11;               // 0:q 1:k 2:v
    if (sel == 2) {
#pragma unroll
        for (int mf = 0; mf < 4; ++mf)
#pragma unroll
            for (int nf = 0; nf < 4; ++nf) {
                const int row = m0 + mhalf * 64 + mf * 16 + quad * 4;
                const int colv = (n0 - 4096) + nhalf * 64 + nf * 16 + l15;
                const int b_ = row >> 11, l_ = row & 2047;
                const int h_ = colv >> 8, d_ = colv & 255;
                us4 pk;
#pragma unroll
                for (int r = 0; r < 4; ++r) pk[r] = f2bf(acc[mf][nf][r]);
                *(us4*)((ushort_t*)C2 +
                        (((size_t)(b_ * 8 + h_) * 256 + d_) * 2048 + l_)) = pk;
            }
    } else {
        ushort_t* dst = sel ? (ushort_t*)C1 : (ushort_t*)C0;
#pragma unroll
        for (int mf = 0; mf < 4; ++mf)
#pragma unroll
            for (int nf = 0; nf < 4; ++nf)
#pragma unroll
                for (int r = 0; r < 4; ++r) {
                    const int row = m0 + mhalf * 64 + mf * 16 + quad * 4 + r;
                    const int col = (n0 & 2047) + nhalf * 64 + nf * 16 + l15;
                    dst[(size_t)row * 2048 + col] = f2bf(acc[mf][nf][r]);
                }
    }
}

// ---------------------------------------------------------------------------
// Output projection GEMM, 64x128 tile (grid 128x2 = 256 blocks -> all CUs).
// ---------------------------------------------------------------------------
__global__ __launch_bounds__(256, 4) void gemm_out_kernel(
    const ushort_t* __restrict__ A, const ushort_t* __restrict__ Bm,
    float* __restrict__ C)
{
    __shared__ ushort_t At[64 * 64];    // 8 KB
    __shared__ ushort_t Bt[128 * 64];   // 16 KB

    const int tid  = threadIdx.x;
    const int wave = tid >> 6;
    const int lane = tid & 63;
    const int quad = lane >> 4;
    const int l15  = lane & 15;
    const int mhalf = wave >> 1;
    const int nhalf = wave & 1;
    const int m0 = blockIdx.x * 64;
    const int n0 = blockIdx.y * 128;

    f32x4 acc[2][4];
#pragma unroll
    for (int mf = 0; mf < 2; ++mf)
#pragma unroll
        for (int nf = 0; nf < 4; ++nf)
#pragma unroll
            for (int r = 0; r < 4; ++r) acc[mf][nf][r] = 0.f;

    const int crow = (lane & 7) ^ (lane >> 3);

    for (int k0 = 0; k0 < 2048; k0 += 64) {
        __syncthreads();
#pragma unroll
        for (int t = 0; t < 2; ++t) {
            const int row = wave * 16 + t * 8 + (lane >> 3);
            async16(A + (size_t)(m0 + row) * 2048 + k0 + crow * 8,
                    At + (wave * 16 + t * 8) * 64 + lane * 8);
        }
#pragma unroll
        for (int t = 0; t < 4; ++t) {
            const int row = wave * 32 + t * 8 + (lane >> 3);
            async16(Bm + (size_t)(n0 + row) * 2048 + k0 + crow * 8,
                    Bt + (wave * 32 + t * 8) * 64 + lane * 8);
        }
        __syncthreads();
#pragma unroll
        for (int ks = 0; ks < 2; ++ks) {
            bf16x8 af[2], bf[4];
#pragma unroll
            for (int mf = 0; mf < 2; ++mf) {
                const int ml = mhalf * 32 + mf * 16 + l15;
                const int c = (ks * 4 + quad) ^ (ml & 7);
                af[mf] = *(const bf16x8*)(At + ml * 64 + c * 8);
            }
#pragma unroll
            for (int nf = 0; nf < 4; ++nf) {
                const int nl = nhalf * 64 + nf * 16 + l15;
                const int c = (ks * 4 + quad) ^ (nl & 7);
                bf[nf] = *(const bf16x8*)(Bt + nl * 64 + c * 8);
            }
#pragma unroll
            for (int mf = 0; mf < 2; ++mf)
#pragma unroll
                for (int nf = 0; nf < 4; ++nf)
                    acc[mf][nf] = __builtin_amdgcn_mfma_f32_16x16x32_bf16(
                        af[mf], bf[nf], acc[mf][nf], 0, 0, 0);
        }
    }

#pragma unroll
    for (int mf = 0; mf < 2; ++mf)
#pragma unroll
        for (int nf = 0; nf < 4; ++nf)
#pragma unroll
            for (int r = 0; r < 4; ++r) {
                const int row = m0 + mhalf * 32 + mf * 16 + quad * 4 + r;
                const int col = n0 + nhalf * 64 + nf * 16 + l15;
                C[(size_t)row * 256 + col] = acc[mf][nf][r];
            }
}

// ---------------------------------------------------------------------------
// Pass 1: full-row softmax denominator Z_i = sum_j exp(s_ij/16).
// (round-4 proven version: async16 staging, 64-row tiles, 4 blocks/CU)
// ---------------------------------------------------------------------------
__global__ __launch_bounds__(256, 4) void pass1_kernel(
    const ushort_t* __restrict__ q_ws, const ushort_t* __restrict__ k_ws,
    float* __restrict__ rz_ws)
{
    __shared__ ushort_t Kt[64 * 256];   // 32 KB, chunk-swizzled
    __shared__ float zred[2][64];

    const float SCALE = 0.0625f;        // 1/sqrt(256)
    const int tid  = threadIdx.x;
    const int wave = tid >> 6;
    const int lane = tid & 63;
    const int quad = lane >> 4;
    const int l15  = lane & 15;
    const int ihalf = wave >> 1;
    const int jhalf = wave & 1;

    const int g  = blockIdx.x;
    const int bh = ((g >> 8) << 3) | (g & 7);
    const int it = (g >> 3) & 31;
    const int b = bh >> 3, h = bh & 7;
    const int i0 = it * 64;

    const size_t qkbase = (size_t)b * 2048 * 2048 + (size_t)h * 256;

    bf16x8 qf[2][8];
#pragma unroll
    for (int ng = 0; ng < 2; ++ng) {
        const int i_l = ihalf * 32 + ng * 16 + l15;
        const ushort_t* qr = q_ws + qkbase + (size_t)(i0 + i_l) * 2048;
#pragma unroll
        for (int ks = 0; ks < 8; ++ks)
            qf[ng][ks] = *(const bf16x8*)(qr + ks * 32 + quad * 8);
    }

    float z[2] = {0.f, 0.f};

    for (int jt = 0; jt < 32; ++jt) {
        const int j0 = jt * 64;
        __syncthreads();
        {
            const ushort_t* kb = k_ws + qkbase + (size_t)j0 * 2048;
#pragma unroll
            for (int t = 0; t < 8; ++t) {
                const int row = wave * 16 + t * 2 + (lane >> 5);
                const int c = (lane & 31) ^ (row & 7);
                async16(kb + (size_t)row * 2048 + c * 8,
                        Kt + (wave * 16 + t * 2) * 256 + lane * 8);
            }
        }
        __syncthreads();

        f32x4 sacc[2][2];
#pragma unroll
        for (int a = 0; a < 2; ++a)
#pragma unroll
            for (int c = 0; c < 2; ++c)
#pragma unroll
                for (int r = 0; r < 4; ++r) sacc[a][c][r] = 0.f;

#pragma unroll
        for (int ks = 0; ks < 8; ++ks) {
            bf16x8 af[2];
#pragma unroll
            for (int mg = 0; mg < 2; ++mg) {
                const int j_l = jhalf * 32 + mg * 16 + l15;
                const int c = (ks * 4 + quad) ^ (j_l & 7);
                af[mg] = *(const bf16x8*)(Kt + j_l * 256 + c * 8);
            }
#pragma unroll
            for (int mg = 0; mg < 2; ++mg)
#pragma unroll
                for (int ng = 0; ng < 2; ++ng)
                    sacc[mg][ng] = __builtin_amdgcn_mfma_f32_16x16x32_bf16(
                        af[mg], qf[ng][ks], sacc[mg][ng], 0, 0, 0);
        }

#pragma unroll
        for (int ng = 0; ng < 2; ++ng)
#pragma unroll
            for (int mg = 0; mg < 2; ++mg)
#pragma unroll
                for (int r = 0; r < 4; ++r)
                    z[ng] += __expf(sacc[mg][ng][r] * SCALE);
    }

#pragma unroll
    for (int ng = 0; ng < 2; ++ng) {
        z[ng] += __shfl_xor(z[ng], 16);
        z[ng] += __shfl_xor(z[ng], 32);
    }
    __syncthreads();
    if (quad == 0) {
#pragma unroll
        for (int ng = 0; ng < 2; ++ng) {
            const int i_l = ihalf * 32 + ng * 16 + l15;
            zred[jhalf][i_l] = z[ng];
        }
    }
    __syncthreads();
    if (tid < 64)
        rz_ws[(size_t)bh * 2048 + i0 + tid] = 1.0f / (zred[0][tid] + zred[1][tid]);
}

// ---------------------------------------------------------------------------
// Pass 2: causal w = exp(exp(s/16)/Z); PV; divide by sum(w).
// Double-buffered 32-j tiles staged by global_load_lds (no staging VGPRs).
// Per iter: lgkm-barrier -> issue 8 DMAs for tile t+1 into other buffer ->
// "s_waitcnt vmcnt(8); s_barrier" (tile-t landed; prefetch stays in flight
// through the whole compute phase) -> QK quadrant -> W -> lgkm-barrier -> PV.
// Waves: (ihalf, jhalf); QK 32i x 16j; PV i-half x d-half, K=32.
// ---------------------------------------------------------------------------
__global__ __launch_bounds__(256, 1) void pass2_kernel(
    const ushort_t* __restrict__ q_ws, const ushort_t* __restrict__ k_ws,
    const ushort_t* __restrict__ vt_ws, const float* __restrict__ rz_ws,
    ushort_t* __restrict__ attn_out)
{
    __shared__ ushort_t Kb[2][32 * 256];  // 2 x 16 KB
    __shared__ ushort_t Vb[2][256 * 32];  // 2 x 16 KB
    __shared__ ushort_t Wt[64 * 32];      // 4 KB
    __shared__ float dred[128];

    const float SCALE = 0.0625f;
    const int tid  = threadIdx.x;
    const int wave = tid >> 6;
    const int lane = tid & 63;
    const int quad = lane >> 4;
    const int l15  = lane & 15;
    const int ihalf = wave >> 1;
    const int jhalf = wave & 1;

    const int g  = blockIdx.x;
    const int bh = ((g >> 8) << 3) | (g & 7);
    const int it = 31 - ((g >> 3) & 31);      // heavy blocks dispatched first
    const int b = bh >> 3, h = bh & 7;
    const int i0 = it * 64;
    const int jtmax = 2 * it + 1;             // 32-j tiles

    const size_t qkbase = (size_t)b * 2048 * 2048 + (size_t)h * 256;
    const size_t vtbase = (size_t)bh * 256 * 2048;

    bf16x8 qf[2][8];
#pragma unroll
    for (int ng = 0; ng < 2; ++ng) {
        const int i_l = ihalf * 32 + ng * 16 + l15;
        const ushort_t* qr = q_ws + qkbase + (size_t)(i0 + i_l) * 2048;
#pragma unroll
        for (int ks = 0; ks < 8; ++ks)
            qf[ng][ks] = *(const bf16x8*)(qr + ks * 32 + quad * 8);
    }
    float rzrow[2];
#pragma unroll
    for (int ng = 0; ng < 2; ++ng)
        rzrow[ng] = rz_ws[(size_t)bh * 2048 + i0 + ihalf * 32 + ng * 16 + l15];

    f32x4 oacc[2][8];
#pragma unroll
    for (int mg = 0; mg < 2; ++mg)
#pragma unroll
        for (int nf = 0; nf < 8; ++nf)
#pragma unroll
            for (int r = 0; r < 4; ++r) oacc[mg][nf][r] = 0.f;
    float den[2] = {0.f, 0.f};

    // ---- DMA staging for one 32-j tile: 4 K + 4 V async16 per wave --------
    const int krow_ = wave * 8 + (lane >> 5);            // +t*2
    const int vrow_ = wave * 64 + (lane >> 2);           // +t*16
#define STAGE_TILE(jt_, pb_)                                                  \
    {                                                                         \
        const ushort_t* kb_ = k_ws + qkbase + (size_t)(jt_) * 32 * 2048;      \
        const ushort_t* vb_ = vt_ws + vtbase + (size_t)(jt_) * 32;            \
        _Pragma("unroll")                                                     \
        for (int t = 0; t < 4; ++t) {                                         \
            const int kr = krow_ + t * 2;                                     \
            const int kc = (lane & 31) ^ (kr & 7);                            \
            async16(kb_ + (size_t)kr * 2048 + kc * 8,                         \
                    Kb[pb_] + (wave * 8 + t * 2) * 256 + lane * 8);           \
        }                                                                     \
        _Pragma("unroll")                                                     \
        for (int t = 0; t < 4; ++t) {                                         \
            const int vr = vrow_ + t * 16;                                    \
            const int vc = (lane & 3) ^ ((vr ^ (vr >> 2)) & 3);               \
            async16(vb_ + (size_t)vr * 2048 + vc * 8,                         \
                    Vb[pb_] + (wave * 64 + t * 16) * 32 + lane * 8);          \
        }                                                                     \
    }

    STAGE_TILE(0, 0);                        // prologue: tile 0 -> buf 0

    const int iblo = it * 4 + ihalf * 2;     // wave's first 16-blk of i

    for (int jt = 0; jt <= jtmax; ++jt) {
        const int p = jt & 1;
        barrier_lgkm();                      // all waves done reading buf[1-p]
        if (jt < jtmax) {
            STAGE_TILE(jt + 1, 1 - p);       // 8 new DMAs into other buffer
            barrier_vm8();                   // tile-jt landed; new 8 in flight
        } else {
            barrier_vm0();
        }

        // ---------------- QK quadrant + w ----------------
        const int jb16 = jt * 2 + jhalf;
        if (jb16 <= iblo + 1) {              // not fully masked
            f32x4 sacc[2];
#pragma unroll
            for (int ng = 0; ng < 2; ++ng)
#pragma unroll
                for (int r = 0; r < 4; ++r) sacc[ng][r] = 0.f;
#pragma unroll
            for (int ks = 0; ks < 8; ++ks) {
                const int j_l = jhalf * 16 + l15;
                const int c = (ks * 4 + quad) ^ (j_l & 7);
                const bf16x8 af = *(const bf16x8*)(Kb[p] + j_l * 256 + c * 8);
#pragma unroll
                for (int ng = 0; ng < 2; ++ng)
                    sacc[ng] = __builtin_amdgcn_mfma_f32_16x16x32_bf16(
                        af, qf[ng][ks], sacc[ng], 0, 0, 0);
            }
            const bool need_mask = (jb16 >= iblo);
#pragma unroll
            for (int ng = 0; ng < 2; ++ng) {
                const int di = (i0 + ihalf * 32 + ng * 16 + l15)
                             - (jt * 32 + jhalf * 16 + quad * 4);
                us4 wp;
#pragma unroll
                for (int r = 0; r < 4; ++r) {
                    const float pr = __expf(sacc[ng][r] * SCALE) * rzrow[ng];
                    float w = __expf(pr);
                    if (need_mask && (r > di)) w = 0.f;
                    den[ng] += w;
                    wp[r] = f2bf(w);
                }
                const int row = ihalf * 32 + ng * 16 + l15;
                const int c = (jhalf * 4 + quad) ^ (l15 & 7);
                *(us4*)(Wt + row * 32 + c * 4) = wp;
            }
        } else {                             // fully masked quadrant: zero W
            const us4 zz = {0, 0, 0, 0};
#pragma unroll
            for (int ng = 0; ng < 2; ++ng) {
                const int row = ihalf * 32 + ng * 16 + l15;
                const int c = (jhalf * 4 + quad) ^ (l15 & 7);
                *(us4*)(Wt + row * 32 + c * 4) = zz;
            }
        }
        barrier_lgkm();                      // W visible; prefetch still in flight

        // ---------------- PV: i-half (ihalf) x d-half (jhalf) --------------
        if (jt <= it * 2 + ihalf) {          // any unmasked j for this i-half
            bf16x8 aw[2];
#pragma unroll
            for (int mg = 0; mg < 2; ++mg) {
                const int row = ihalf * 32 + mg * 16 + l15;
                const s16x4 lo = *(const s16x4*)(Wt + row * 32 + ((2 * quad)     ^ (l15 & 7)) * 4);
                const s16x4 hi = *(const s16x4*)(Wt + row * 32 + ((2 * quad + 1) ^ (l15 & 7)) * 4);
                union { s16x4 hh[2]; bf16x8 v; } u;
                u.hh[0] = lo; u.hh[1] = hi;
                aw[mg] = u.v;
            }
#pragma unroll
            for (int nf = 0; nf < 8; ++nf) {
                const int d = jhalf * 128 + nf * 16 + l15;
                const int c = quad ^ ((d ^ (d >> 2)) & 3);
                const bf16x8 bv = *(const bf16x8*)(Vb[p] + d * 32 + c * 8);
                oacc[0][nf] = __builtin_amdgcn_mfma_f32_16x16x32_bf16(aw[0], bv, oacc[0][nf], 0, 0, 0);
                oacc[1][nf] = __builtin_amdgcn_mfma_f32_16x16x32_bf16(aw[1], bv, oacc[1][nf], 0, 0, 0);
            }
        }
    }
#undef STAGE_TILE

    // ---------------- epilogue: merge den across jhalf, scale, store --------
#pragma unroll
    for (int ng = 0; ng < 2; ++ng) {
        den[ng] += __shfl_xor(den[ng], 16);
        den[ng] += __shfl_xor(den[ng], 32);
    }
    __syncthreads();
    if (quad == 0) {
#pragma unroll
        for (int ng = 0; ng < 2; ++ng)
            dred[(ihalf * 2 + jhalf) * 32 + ng * 16 + l15] = den[ng];
    }
    __syncthreads();
#pragma unroll
    for (int mg = 0; mg < 2; ++mg) {
#pragma unroll
        for (int r = 0; r < 4; ++r) {
            const int il = mg * 16 + quad * 4 + r;
            const float dt = dred[(ihalf * 2) * 32 + il] + dred[(ihalf * 2 + 1) * 32 + il];
            const float rd = 1.0f / dt;
            ushort_t* orow = attn_out + qkbase + (size_t)(i0 + ihalf * 32 + il) * 2048;
#pragma unroll
            for (int nf = 0; nf < 8; ++nf)
                orow[jhalf * 128 + nf * 16 + l15] = f2bf(oacc[mg][nf][r] * rd);
        }
    }
}

// ---------------------------------------------------------------------------
extern "C" void kernel_launch(void* const* d_in, const int* in_sizes, int n_in,
                              void* d_out, int out_size, void* d_ws, size_t ws_size,
                              hipStream_t stream) {
    const float* x  = (const float*)d_in[0];
    const float* Wq = (const float*)d_in[1];
    const float* Wk = (const float*)d_in[2];
    const float* Wv = (const float*)d_in[3];
    const float* Wo = (const float*)d_in[4];

    char* ws = (char*)d_ws;
    ushort_t* xb    = (ushort_t*)(ws);
    ushort_t* wqb   = (ushort_t*)(ws + 4194304);   // wq/wk/wv contiguous -> [6144][256]
    ushort_t* wkb   = (ushort_t*)(ws + 5242880);
    ushort_t* wvb   = (ushort_t*)(ws + 6291456);
    ushort_t* wob   = (ushort_t*)(ws + 7340032);
    ushort_t* q_ws  = (ushort_t*)(ws + 8388608);
    ushort_t* k_ws  = (ushort_t*)(ws + 41943040);
    ushort_t* vt_ws = (ushort_t*)(ws + 75497472);
    ushort_t* ao_ws = (ushort_t*)(ws + 109051904);
    float*    rz_ws = (float*)   (ws + 142606336);

    convert_kernel<<<4096, 256, 0, stream>>>(x, Wq, Wk, Wv, Wo, xb, wqb, wkb, wvb, wob);

    gemm_qkv_kernel<<<dim3(64, 48), 256, 0, stream>>>(xb, wqb, q_ws, k_ws, vt_ws);

    pass1_kernel<<<1024, 256, 0, stream>>>(q_ws, k_ws, rz_ws);
    pass2_kernel<<<1024, 256, 0, stream>>>(q_ws, k_ws, vt_ws, rz_ws, ao_ws);

    gemm_out_kernel<<<dim3(128, 2), 256, 0, stream>>>(ao_ws, wob, (float*)d_out);
}